// Round 1
// baseline (1017.578 us; speedup 1.0000x reference)
//
#include <hip/hip_runtime.h>

#define BATCH 64
#define SEQ 729
#define DIM 64
#define QT 12          // q tiles of 64
#define NKT 12         // k tiles of 64
#define KSPLIT 2       // k-dim split across blocks (occupancy lever)
#define KT (NKT / KSPLIT)   // 6 k-tiles per block (even: ping-pong unroll by 2)
#define STRB 72        // bf16 LDS row stride (Ks/Vs/Ps)

typedef __attribute__((ext_vector_type(8))) short bf16x8;
typedef __attribute__((ext_vector_type(4))) float f32x4;

__device__ __forceinline__ unsigned short f2bf(float f) {
    unsigned int u = __float_as_uint(f);
    u += 0x7fffu + ((u >> 16) & 1u);   // round-to-nearest-even
    return (unsigned short)(u >> 16);
}

__device__ __forceinline__ unsigned long long pack4bf(float a, float b, float c, float d) {
    return (unsigned long long)f2bf(a)
         | ((unsigned long long)f2bf(b) << 16)
         | ((unsigned long long)f2bf(c) << 32)
         | ((unsigned long long)f2bf(d) << 48);
}

// tanh(x) = 1 - 2/(exp2(2x*log2e)+1)
__device__ __forceinline__ float fast_tanh(float x) {
    float e = __builtin_amdgcn_exp2f(x * 2.88539008177792681f);
    return 1.0f - 2.0f * __builtin_amdgcn_rcpf(e + 1.0f);
}

// launch_bounds(256,4): 4 blocks/CU (16 waves) -> VGPR capped at 128.
// LDS = 3*9216 = 27648 B -> LDS allows 5 blocks; VGPR is the 4-block limiter.
__global__ __launch_bounds__(256, 4) void attn_kernel(
    const float* __restrict__ Qg, const float* __restrict__ Kg,
    const float* __restrict__ Vg, const int* __restrict__ Mg,
    float* __restrict__ Og, float* __restrict__ Ag)
{
    __shared__ unsigned short Ks[64 * STRB];  // [k][d] bf16
    __shared__ unsigned short Vs[64 * STRB];  // [d][k] bf16 (transposed)
    __shared__ unsigned short Ps[64 * STRB];  // Q bf16 (prologue), then P bf16 (wave-private rows)

    const int tid = threadIdx.x;
    const int q0  = blockIdx.x * 64;
    const int b   = blockIdx.y;
    const int kt0 = blockIdx.z * KT;          // this block's first k-tile

    const float* Qb = Qg + (size_t)b * SEQ * DIM;
    const float* Kb = Kg + (size_t)b * SEQ * DIM;
    const float* Vb = Vg + (size_t)b * SEQ * DIM;
    const int*   Mb = Mg + (size_t)b * SEQ * SEQ;
    float* Ob = Og + (size_t)b * SEQ * DIM;
    float* Ab = Ag + (size_t)b * SEQ * SEQ;

    const int lane = tid & 63;
    const int quad = lane >> 4;
    const int l15  = lane & 15;
    const int qrow = (tid >> 6) * 16;      // wave's q-strip base (local)

    // block-cooperative K staging: 16 consecutive threads cover one row's 64
    // cols -> 256B contiguous segments, float4 per lane
    const int rr = tid >> 4;               // row group 0..15 (+16*i)
    const int cc = (tid & 15) * 4;         // col (floats)
    // V staging (transposed-store scheme, 256B-coalesced loads)
    const int vd0 = (tid & 15) * 4;        // dims
    const int vk0 = (tid >> 4) * 4;        // k rows

    float4 kr[4], vr[4];
    int m0[16], m1[16];                    // mask double-buffer, MFMA consumption layout

    auto load_k = [&](int k0n) {
        #pragma unroll
        for (int i = 0; i < 4; ++i) {
            int gk = k0n + rr + 16 * i;
            kr[i] = (gk < SEQ) ? *(const float4*)(Kb + gk * DIM + cc)
                               : float4{0, 0, 0, 0};
        }
    };
    auto load_v = [&](int k0n) {
        #pragma unroll
        for (int i = 0; i < 4; ++i) {
            int gk = k0n + vk0 + i;
            vr[i] = (gk < SEQ) ? *(const float4*)(Vb + gk * DIM + vd0)
                               : float4{0, 0, 0, 0};
        }
    };
    // mask loaded directly in the lanes/regs that consume it (no LDS round-trip)
    // per (r,n): 16-lane row-groups read 64B contiguous -> coalesced dwords
    auto load_mask = [&](int k0n, int (&dst)[16]) {
        #pragma unroll
        for (int r = 0; r < 4; ++r) {
            int gq = q0 + qrow + quad * 4 + r;
            int cq = gq < SEQ ? gq : SEQ - 1;      // clamp: value unused when OOB
            const int* Mrow = Mb + (size_t)cq * SEQ;
            #pragma unroll
            for (int n = 0; n < 4; ++n) {
                int gk = k0n + n * 16 + l15;
                int ck = gk < SEQ ? gk : SEQ - 1;
                dst[r * 4 + n] = Mrow[ck];
            }
        }
    };
    auto drain_kv = [&]() {
        #pragma unroll
        for (int i = 0; i < 4; ++i)
            *(unsigned long long*)&Ks[(rr + 16 * i) * STRB + cc] =
                pack4bf(kr[i].x, kr[i].y, kr[i].z, kr[i].w);
        #pragma unroll
        for (int j = 0; j < 4; ++j) {
            float v0 = j==0?vr[0].x:j==1?vr[0].y:j==2?vr[0].z:vr[0].w;
            float v1 = j==0?vr[1].x:j==1?vr[1].y:j==2?vr[1].z:vr[1].w;
            float v2 = j==0?vr[2].x:j==1?vr[2].y:j==2?vr[2].z:vr[2].w;
            float v3 = j==0?vr[3].x:j==1?vr[3].y:j==2?vr[3].z:vr[3].w;
            *(unsigned long long*)&Vs[(vd0 + j) * STRB + vk0] = pack4bf(v0, v1, v2, v3);
        }
    };

    // ---- stage Q tile into Ps (256B-coalesced float4 loads) ----
    #pragma unroll
    for (int i = 0; i < 4; ++i) {
        int gq = q0 + rr + 16 * i;
        float4 x = (gq < SEQ) ? *(const float4*)(Qb + gq * DIM + cc)
                              : float4{0, 0, 0, 0};
        *(unsigned long long*)&Ps[(rr + 16 * i) * STRB + cc] = pack4bf(x.x, x.y, x.z, x.w);
    }
    __syncthreads();

    // hoist loop-invariant Q fragments (wave-private rows); Ps becomes P buffer
    const bf16x8 aq0 = *(const bf16x8*)&Ps[(qrow + l15) * STRB + quad * 8];
    const bf16x8 aq1 = *(const bf16x8*)&Ps[(qrow + l15) * STRB + 32 + quad * 8];

    // preload first tile into regs
    load_k(kt0 * 64); load_v(kt0 * 64); load_mask(kt0 * 64, m0);

    f32x4 oacc[4];
    #pragma unroll
    for (int dt = 0; dt < 4; ++dt) {
        oacc[dt][0]=0.f; oacc[dt][1]=0.f; oacc[dt][2]=0.f; oacc[dt][3]=0.f;
    }

    auto tile = [&](int t, int (&mc)[16], int (&mn)[16]) {
        const int k0 = (kt0 + t) * 64;

        __syncthreads();            // prev tile's Ks/Vs readers done
        drain_kv();                 // regs (tile t) -> LDS (waits vmcnt here)
        __syncthreads();            // staging visible

        // prefetch tile t+1 into regs (lands during compute below)
        if (t + 1 < KT) {
            load_k(k0 + 64); load_v(k0 + 64); load_mask(k0 + 64, mn);
        }

        // ---- QK^T ----
        f32x4 sacc[4];
        #pragma unroll
        for (int n = 0; n < 4; ++n) {
            bf16x8 bk0 = *(const bf16x8*)&Ks[(n * 16 + l15) * STRB + quad * 8];
            bf16x8 bk1 = *(const bf16x8*)&Ks[(n * 16 + l15) * STRB + 32 + quad * 8];
            f32x4 c; c[0]=0.f; c[1]=0.f; c[2]=0.f; c[3]=0.f;
            c = __builtin_amdgcn_mfma_f32_16x16x32_bf16(aq0, bk0, c, 0, 0, 0);
            c = __builtin_amdgcn_mfma_f32_16x16x32_bf16(aq1, bk1, c, 0, 0, 0);
            sacc[n] = c;
        }

        // ---- scale, mask (regs), tanh, zero-diag; write P bf16 + attn direct ----
        #pragma unroll
        for (int n = 0; n < 4; ++n) {
            const int col = n * 16 + l15;
            const int gk  = k0 + col;
            #pragma unroll
            for (int r = 0; r < 4; ++r) {
                const int qloc = qrow + quad * 4 + r;
                const int gq   = q0 + qloc;
                const int m    = mc[r * 4 + n];
                float sv = sacc[n][r] * 0.125f;       // 1/sqrt(64)
                bool msk = (m == 0);
                float p = fast_tanh(msk ? -1e9f : sv);
                if (msk) p = -1.0f;
                if (gq == gk) p = 0.0f;               // ignore_diag
                if (gq >= SEQ || gk >= SEQ) p = 0.0f; // padding
                Ps[qloc * STRB + col] = f2bf(p);
                // direct store in C-layout: 16-lane row-groups -> 64B segments
                if (gq < SEQ && gk < SEQ)
                    Ab[(size_t)gq * SEQ + gk] = p;
            }
        }

        // ---- PV ----
        const bf16x8 ap0 = *(const bf16x8*)&Ps[(qrow + l15) * STRB + quad * 8];
        const bf16x8 ap1 = *(const bf16x8*)&Ps[(qrow + l15) * STRB + 32 + quad * 8];
        #pragma unroll
        for (int dt = 0; dt < 4; ++dt) {
            bf16x8 bv0 = *(const bf16x8*)&Vs[(dt * 16 + l15) * STRB + quad * 8];
            bf16x8 bv1 = *(const bf16x8*)&Vs[(dt * 16 + l15) * STRB + 32 + quad * 8];
            oacc[dt] = __builtin_amdgcn_mfma_f32_16x16x32_bf16(ap0, bv0, oacc[dt], 0, 0, 0);
            oacc[dt] = __builtin_amdgcn_mfma_f32_16x16x32_bf16(ap1, bv1, oacc[dt], 0, 0, 0);
        }
    };

    // ping-pong mask buffers via 2x unroll (no runtime-indexed arrays, no copies)
    for (int t = 0; t < KT; t += 2) {
        tile(t,     m0, m1);
        tile(t + 1, m1, m0);
    }

    // ---- O epilogue: k-split partials combined via atomics (Out pre-zeroed) ----
    #pragma unroll
    for (int dt = 0; dt < 4; ++dt) {
        #pragma unroll
        for (int r = 0; r < 4; ++r) {
            const int gq = q0 + qrow + quad * 4 + r;
            if (gq < SEQ)
                atomicAdd(Ob + (size_t)gq * DIM + dt * 16 + l15, oacc[dt][r]);
        }
    }
}

extern "C" void kernel_launch(void* const* d_in, const int* in_sizes, int n_in,
                              void* d_out, int out_size, void* d_ws, size_t ws_size,
                              hipStream_t stream) {
    const float* Q = (const float*)d_in[0];
    const float* K = (const float*)d_in[1];
    const float* V = (const float*)d_in[2];
    const int*   M = (const int*)d_in[3];
    float* Out  = (float*)d_out;
    float* Attn = Out + (size_t)BATCH * SEQ * DIM;   // tuple order: (out, attention)
    // zero O for cross-block k-split accumulation (async, graph-capture-safe)
    hipMemsetAsync(Out, 0, (size_t)BATCH * SEQ * DIM * sizeof(float), stream);
    dim3 grid(QT, BATCH, KSPLIT);
    attn_kernel<<<grid, 256, 0, stream>>>(Q, K, V, M, Out, Attn);
}

// Round 2
// 511.133 us; speedup vs baseline: 1.9908x; 1.9908x over previous
//
#include <hip/hip_runtime.h>

#define BATCH 64
#define SEQ 729
#define DIM 64
#define QT 12          // q tiles of 64
#define NKT 12         // k tiles of 64
#define KSPLIT 2       // k-split across blocks (occupancy lever)
#define KT (NKT / KSPLIT)
#define STRB 72        // bf16 LDS row stride (Ks/Vs/Ps): 144B rows, 16B-aligned
#define MSTR 68        // mask byte-row stride
#define OSTR 68        // epilogue fp32 dword-row stride (272B rows, 16B-aligned)

typedef __attribute__((ext_vector_type(8))) short bf16x8;
typedef __attribute__((ext_vector_type(4))) float f32x4;
// 4B-aligned vector views for 729-strided global rows (rows only dword-aligned)
typedef int   i32x4a __attribute__((ext_vector_type(4), aligned(4)));
typedef float f32x4a __attribute__((ext_vector_type(4), aligned(4)));

__device__ __forceinline__ unsigned short f2bf(float f) {
    unsigned int u = __float_as_uint(f);
    u += 0x7fffu + ((u >> 16) & 1u);   // round-to-nearest-even
    return (unsigned short)(u >> 16);
}

__device__ __forceinline__ unsigned long long pack4bf(float a, float b, float c, float d) {
    return (unsigned long long)f2bf(a)
         | ((unsigned long long)f2bf(b) << 16)
         | ((unsigned long long)f2bf(c) << 32)
         | ((unsigned long long)f2bf(d) << 48);
}

__device__ __forceinline__ float bf2f(unsigned int hi16) {
    return __uint_as_float(hi16 << 16);
}

// tanh(x) = 1 - 2/(exp2(2x*log2e)+1)
__device__ __forceinline__ float fast_tanh(float x) {
    float e = __builtin_amdgcn_exp2f(x * 2.88539008177792681f);
    return 1.0f - 2.0f * __builtin_amdgcn_rcpf(e + 1.0f);
}

// LDS budget: Ks 9216 + Vs 9216 + Ps 9216 + mask 4352 = 32000 B -> 5 blocks/CU.
// Epilogue O staging (64x68 fp32 = 17408B) overlays the then-dead Ks+Vs region.
__global__ __launch_bounds__(256, 5) void attn_kernel(
    const float* __restrict__ Qg, const float* __restrict__ Kg,
    const float* __restrict__ Vg, const int* __restrict__ Mg,
    float* __restrict__ Og, float* __restrict__ Ag)
{
    __shared__ __align__(16) unsigned char smem[32000];
    unsigned short* Ks  = (unsigned short*)(smem);           // [k][d] bf16
    unsigned short* Vs  = (unsigned short*)(smem + 9216);    // [d][k] bf16 (transposed)
    unsigned short* Ps  = (unsigned short*)(smem + 18432);   // Q bf16, then P bf16
    unsigned char*  Mb8 = smem + 27648;                      // [q][k] mask bytes
    float* Ostage = (float*)smem;                            // epilogue overlay (Ks+Vs)

    const int tid = threadIdx.x;
    const int q0  = blockIdx.x * 64;
    const int b   = blockIdx.y;
    const int kt0 = blockIdx.z * KT;

    const float* Qb = Qg + (size_t)b * SEQ * DIM;
    const float* Kb = Kg + (size_t)b * SEQ * DIM;
    const float* Vb = Vg + (size_t)b * SEQ * DIM;
    const int*   Mb = Mg + (size_t)b * SEQ * SEQ;
    float* Ob = Og + (size_t)b * SEQ * DIM;
    float* Ab = Ag + (size_t)b * SEQ * SEQ;

    const int lane = tid & 63;
    const int quad = lane >> 4;
    const int l15  = lane & 15;
    const int qrow = (tid >> 6) * 16;      // wave's q-strip base (local)

    // block-cooperative staging: 16 consecutive threads cover one row's 64
    // cols -> 256B contiguous segments, float4 per lane (KEEP: round-1 showed
    // 64B scalar segments amplify HBM traffic 5-10x on this chip)
    const int rr = tid >> 4;               // row group 0..15 (+16*i)
    const int cc = (tid & 15) * 4;         // col (floats)
    const int vd0 = (tid & 15) * 4;        // V: dims
    const int vk0 = (tid >> 4) * 4;        // V: k rows
    // wave-private mask/attn row geometry: 16 lanes cover one row's 64 cols
    const int prow = qrow + (lane >> 4);   // + 4*i -> rows qrow..qrow+15
    const int pcol = (lane & 15) * 4;

    float4 kr[4], vr[4];
    i32x4a mr[4];

    auto load_k = [&](int k0n) {
        #pragma unroll
        for (int i = 0; i < 4; ++i) {
            int gk = k0n + rr + 16 * i;
            kr[i] = (gk < SEQ) ? *(const float4*)(Kb + gk * DIM + cc)
                               : float4{0, 0, 0, 0};
        }
    };
    auto load_v = [&](int k0n) {
        #pragma unroll
        for (int i = 0; i < 4; ++i) {
            int gk = k0n + vk0 + i;
            vr[i] = (gk < SEQ) ? *(const float4*)(Vb + gk * DIM + vd0)
                               : float4{0, 0, 0, 0};
        }
    };
    auto load_mask = [&](int k0n) {
        #pragma unroll
        for (int i = 0; i < 4; ++i) {
            int gq = q0 + prow + 4 * i;
            int gk = k0n + pcol;
            if (gq < SEQ && gk + 3 < SEQ) {
                mr[i] = *(const i32x4a*)(Mb + (size_t)gq * SEQ + gk);
            } else if (gq < SEQ) {
                i32x4a t;
                #pragma unroll
                for (int e = 0; e < 4; ++e)
                    t[e] = (gk + e < SEQ) ? Mb[(size_t)gq * SEQ + gk + e] : 0;
                mr[i] = t;
            } else {
                mr[i] = i32x4a{0, 0, 0, 0};
            }
        }
    };
    auto drain_mask = [&]() {   // pack 0/1 ints to bytes; wave-private rows
        #pragma unroll
        for (int i = 0; i < 4; ++i) {
            unsigned int mb = (unsigned)(mr[i][0] & 1)
                            | ((unsigned)(mr[i][1] & 1) << 8)
                            | ((unsigned)(mr[i][2] & 1) << 16)
                            | ((unsigned)(mr[i][3] & 1) << 24);
            *(unsigned int*)&Mb8[(prow + 4 * i) * MSTR + pcol] = mb;
        }
    };
    auto drain_kv = [&]() {
        #pragma unroll
        for (int i = 0; i < 4; ++i)
            *(unsigned long long*)&Ks[(rr + 16 * i) * STRB + cc] =
                pack4bf(kr[i].x, kr[i].y, kr[i].z, kr[i].w);
        #pragma unroll
        for (int j = 0; j < 4; ++j) {
            float v0 = j==0?vr[0].x:j==1?vr[0].y:j==2?vr[0].z:vr[0].w;
            float v1 = j==0?vr[1].x:j==1?vr[1].y:j==2?vr[1].z:vr[1].w;
            float v2 = j==0?vr[2].x:j==1?vr[2].y:j==2?vr[2].z:vr[2].w;
            float v3 = j==0?vr[3].x:j==1?vr[3].y:j==2?vr[3].z:vr[3].w;
            *(unsigned long long*)&Vs[(vd0 + j) * STRB + vk0] = pack4bf(v0, v1, v2, v3);
        }
    };

    // ---- stage Q tile into Ps (256B-coalesced float4 loads) ----
    #pragma unroll
    for (int i = 0; i < 4; ++i) {
        int gq = q0 + rr + 16 * i;
        float4 x = (gq < SEQ) ? *(const float4*)(Qb + gq * DIM + cc)
                              : float4{0, 0, 0, 0};
        *(unsigned long long*)&Ps[(rr + 16 * i) * STRB + cc] = pack4bf(x.x, x.y, x.z, x.w);
    }
    __syncthreads();

    // hoist loop-invariant Q fragments; Ps becomes the P bf16 buffer
    const bf16x8 aq0 = *(const bf16x8*)&Ps[(qrow + l15) * STRB + quad * 8];
    const bf16x8 aq1 = *(const bf16x8*)&Ps[(qrow + l15) * STRB + 32 + quad * 8];

    // preload first tile into regs
    load_k(kt0 * 64); load_v(kt0 * 64); load_mask(kt0 * 64);

    f32x4 oacc[4];
    #pragma unroll
    for (int dt = 0; dt < 4; ++dt) {
        oacc[dt][0]=0.f; oacc[dt][1]=0.f; oacc[dt][2]=0.f; oacc[dt][3]=0.f;
    }

    for (int t = 0; t < KT; ++t) {
        const int k0 = (kt0 + t) * 64;

        __syncthreads();            // prev tile's Ks/Vs readers done
        drain_mask();               // regs (tile t) -> LDS
        drain_kv();
        __syncthreads();            // staging visible

        // prefetch tile t+1 into regs (lands during compute below)
        if (t + 1 < KT) {
            load_k(k0 + 64); load_v(k0 + 64); load_mask(k0 + 64);
        }

        // ---- QK^T ----
        f32x4 sacc[4];
        #pragma unroll
        for (int n = 0; n < 4; ++n) {
            bf16x8 bk0 = *(const bf16x8*)&Ks[(n * 16 + l15) * STRB + quad * 8];
            bf16x8 bk1 = *(const bf16x8*)&Ks[(n * 16 + l15) * STRB + 32 + quad * 8];
            f32x4 c; c[0]=0.f; c[1]=0.f; c[2]=0.f; c[3]=0.f;
            c = __builtin_amdgcn_mfma_f32_16x16x32_bf16(aq0, bk0, c, 0, 0, 0);
            c = __builtin_amdgcn_mfma_f32_16x16x32_bf16(aq1, bk1, c, 0, 0, 0);
            sacc[n] = c;
        }

        // ---- scale, mask (LDS bytes), tanh, zero-diag; write P bf16 ----
        #pragma unroll
        for (int n = 0; n < 4; ++n) {
            int col = n * 16 + l15;
            int gk  = k0 + col;
            #pragma unroll
            for (int r = 0; r < 4; ++r) {
                int qloc = qrow + quad * 4 + r;
                int gq = q0 + qloc;
                int m = Mb8[qloc * MSTR + col];
                float sv = sacc[n][r] * 0.125f;       // 1/sqrt(64)
                bool msk = (m == 0);
                float p = fast_tanh(msk ? -1e9f : sv);
                if (msk) p = -1.0f;
                if (gq == gk) p = 0.0f;               // ignore_diag
                if (gq >= SEQ || gk >= SEQ) p = 0.0f; // padding
                Ps[qloc * STRB + col] = f2bf(p);
            }
        }

        // ---- attention write-out from bf16 Ps (same values PV consumes):
        //      wave-private rows, row-contiguous float4 -> 256B segments ----
        #pragma unroll
        for (int i = 0; i < 4; ++i) {
            int row = prow + 4 * i;
            int gq  = q0 + row;
            int gk  = k0 + pcol;
            unsigned long long w = *(const unsigned long long*)&Ps[row * STRB + pcol];
            f32x4 pv;
            pv[0] = bf2f((unsigned)(w      ) & 0xffffu);
            pv[1] = bf2f((unsigned)(w >> 16) & 0xffffu);
            pv[2] = bf2f((unsigned)(w >> 32) & 0xffffu);
            pv[3] = bf2f((unsigned)(w >> 48) & 0xffffu);
            if (gq < SEQ) {
                if (gk + 3 < SEQ) {
                    *(f32x4a*)(Ab + (size_t)gq * SEQ + gk) = pv;
                } else {
                    #pragma unroll
                    for (int e = 0; e < 4; ++e)
                        if (gk + e < SEQ) Ab[(size_t)gq * SEQ + gk + e] = pv[e];
                }
            }
        }

        // ---- PV ----
        const bf16x8 ap0 = *(const bf16x8*)&Ps[(qrow + l15) * STRB + quad * 8];
        const bf16x8 ap1 = *(const bf16x8*)&Ps[(qrow + l15) * STRB + 32 + quad * 8];
        #pragma unroll
        for (int dt = 0; dt < 4; ++dt) {
            bf16x8 bv0 = *(const bf16x8*)&Vs[(dt * 16 + l15) * STRB + quad * 8];
            bf16x8 bv1 = *(const bf16x8*)&Vs[(dt * 16 + l15) * STRB + 32 + quad * 8];
            oacc[dt] = __builtin_amdgcn_mfma_f32_16x16x32_bf16(ap0, bv0, oacc[dt], 0, 0, 0);
            oacc[dt] = __builtin_amdgcn_mfma_f32_16x16x32_bf16(ap1, bv1, oacc[dt], 0, 0, 0);
        }
    }

    // ---- O epilogue: stage via LDS (Ks+Vs overlay), then ROW-LINEAR atomics:
    //      each instruction = 64 consecutive dwords of one row (256B) ----
    __syncthreads();                       // all waves done reading Ks/Vs
    #pragma unroll
    for (int dt = 0; dt < 4; ++dt)
        #pragma unroll
        for (int r = 0; r < 4; ++r)
            Ostage[(qrow + quad * 4 + r) * OSTR + dt * 16 + l15] = oacc[dt][r];
    // wave-private strip: no further barrier needed
    #pragma unroll
    for (int r16 = 0; r16 < 16; ++r16) {
        int row = qrow + r16;
        int gq  = q0 + row;
        float val = Ostage[row * OSTR + lane];
        if (gq < SEQ)
            atomicAdd(Ob + (size_t)gq * DIM + lane, val);
    }
}

extern "C" void kernel_launch(void* const* d_in, const int* in_sizes, int n_in,
                              void* d_out, int out_size, void* d_ws, size_t ws_size,
                              hipStream_t stream) {
    const float* Q = (const float*)d_in[0];
    const float* K = (const float*)d_in[1];
    const float* V = (const float*)d_in[2];
    const int*   M = (const int*)d_in[3];
    float* Out  = (float*)d_out;
    float* Attn = Out + (size_t)BATCH * SEQ * DIM;   // tuple order: (out, attention)
    // zero O for cross-block k-split accumulation (async, graph-capture-safe)
    hipMemsetAsync(Out, 0, (size_t)BATCH * SEQ * DIM * sizeof(float), stream);
    dim3 grid(QT, BATCH, KSPLIT);
    attn_kernel<<<grid, 256, 0, stream>>>(Q, K, V, M, Out, Attn);
}

// Round 3
// 405.597 us; speedup vs baseline: 2.5088x; 1.2602x over previous
//
#include <hip/hip_runtime.h>

#define BATCH 64
#define SEQ 729
#define DIM 64
#define NT 12      // ceil(729/64)
#define STRB 72    // bf16 LDS row stride (Ks/Vs/Qs)
#define STRW 68    // dword LDS row stride (mask/P fp32 tile): 16B-aligned rows

typedef __attribute__((ext_vector_type(8))) short bf16x8;
typedef __attribute__((ext_vector_type(4))) float f32x4;
// 4B-aligned vector views for the 729-strided global rows
typedef int   i32x4a __attribute__((ext_vector_type(4), aligned(4)));
typedef float f32x4a __attribute__((ext_vector_type(4), aligned(4)));

__device__ __forceinline__ unsigned short f2bf(float f) {
    unsigned int u = __float_as_uint(f);
    u += 0x7fffu + ((u >> 16) & 1u);   // round-to-nearest-even
    return (unsigned short)(u >> 16);
}

__device__ __forceinline__ unsigned long long pack4bf(float a, float b, float c, float d) {
    return (unsigned long long)f2bf(a)
         | ((unsigned long long)f2bf(b) << 16)
         | ((unsigned long long)f2bf(c) << 32)
         | ((unsigned long long)f2bf(d) << 48);
}

// tanh(x) = 1 - 2/(exp2(2x*log2e)+1)
__device__ __forceinline__ float fast_tanh(float x) {
    float e = __builtin_amdgcn_exp2f(x * 2.88539008177792681f);
    return 1.0f - 2.0f * __builtin_amdgcn_rcpf(e + 1.0f);
}

// launch_bounds(256,3): VGPR cap ~170; 2-deep prefetch needs ~135 -> no spill.
// LDS 45KB limits to 3 blocks/CU anyway (grid = 768 = exactly 3/CU).
__global__ __launch_bounds__(256, 3) void attn_kernel(
    const float* __restrict__ Qg, const float* __restrict__ Kg,
    const float* __restrict__ Vg, const int* __restrict__ Mg,
    float* __restrict__ Og, float* __restrict__ Ag)
{
    __shared__ unsigned short Ks[64 * STRB];  // [k][d] bf16
    __shared__ unsigned short Vs[64 * STRB];  // [d][k] bf16 (transposed)
    __shared__ unsigned short Qs[64 * STRB];  // Q bf16, then P bf16 (wave-private rows)
    __shared__ float Pf[64 * STRW];           // mask int, then P fp32 (wave-private rows)
    int* Mint = (int*)Pf;

    const int tid = threadIdx.x;
    const int q0  = blockIdx.x * 64;
    const int b   = blockIdx.y;

    const float* Qb = Qg + (size_t)b * SEQ * DIM;
    const float* Kb = Kg + (size_t)b * SEQ * DIM;
    const float* Vb = Vg + (size_t)b * SEQ * DIM;
    const int*   Mb = Mg + (size_t)b * SEQ * SEQ;
    float* Ob = Og + (size_t)b * SEQ * DIM;
    float* Ab = Ag + (size_t)b * SEQ * SEQ;

    const int lane = tid & 63;
    const int quad = lane >> 4;
    const int l15  = lane & 15;
    const int qrow = (tid >> 6) * 16;      // wave's q-strip base (local)

    // block-cooperative staging geometry: 16 consecutive threads cover one
    // row's 64 cols -> 256B contiguous segments, float4 per lane
    const int rr = tid >> 4;               // row group 0..15 (+16*i)
    const int cc = (tid & 15) * 4;         // col (floats)
    // V staging (row-2 scheme, already 256B-coalesced)
    const int vd0 = (tid & 15) * 4;        // dims
    const int vk0 = (tid >> 4) * 4;        // k rows
    // wave-private mask/P row-major geometry: 16 lanes cover one row's 64 cols
    const int prow = qrow + (lane >> 4);   // + 4*i -> rows qrow..qrow+15
    const int pcol = (lane & 15) * 4;

    // 2-deep prefetch: ping-pong register sets (statically indexed via array-ref
    // params -> no scratch; round-2 lesson: runtime-indexed sets would spill)
    float4 krA[4], vrA[4], krB[4], vrB[4];
    i32x4a mrA[4], mrB[4];

    auto load_k = [&](int k0n, float4 (&kr)[4]) {
        #pragma unroll
        for (int i = 0; i < 4; ++i) {
            int gk = k0n + rr + 16 * i;
            kr[i] = (gk < SEQ) ? *(const float4*)(Kb + gk * DIM + cc)
                               : float4{0, 0, 0, 0};
        }
    };
    auto load_v = [&](int k0n, float4 (&vr)[4]) {
        #pragma unroll
        for (int i = 0; i < 4; ++i) {
            int gk = k0n + vk0 + i;
            vr[i] = (gk < SEQ) ? *(const float4*)(Vb + gk * DIM + vd0)
                               : float4{0, 0, 0, 0};
        }
    };
    auto load_mask = [&](int k0n, i32x4a (&mr)[4]) {
        #pragma unroll
        for (int i = 0; i < 4; ++i) {
            int gq = q0 + prow + 4 * i;
            int gk = k0n + pcol;
            if (gq < SEQ && gk + 3 < SEQ) {
                mr[i] = *(const i32x4a*)(Mb + (size_t)gq * SEQ + gk);
            } else if (gq < SEQ) {
                i32x4a t;
                #pragma unroll
                for (int e = 0; e < 4; ++e)
                    t[e] = (gk + e < SEQ) ? Mb[(size_t)gq * SEQ + gk + e] : 0;
                mr[i] = t;
            } else {
                mr[i] = i32x4a{0, 0, 0, 0};
            }
        }
    };
    auto drain_mask = [&](i32x4a (&mr)[4]) {   // wave-private rows -> no barrier
        #pragma unroll
        for (int i = 0; i < 4; ++i)
            *(i32x4a*)&Mint[(prow + 4 * i) * STRW + pcol] = mr[i];
    };
    auto drain_kv = [&](float4 (&kr)[4], float4 (&vr)[4]) {
        #pragma unroll
        for (int i = 0; i < 4; ++i)
            *(unsigned long long*)&Ks[(rr + 16 * i) * STRB + cc] =
                pack4bf(kr[i].x, kr[i].y, kr[i].z, kr[i].w);
        #pragma unroll
        for (int j = 0; j < 4; ++j) {
            float v0 = j==0?vr[0].x:j==1?vr[0].y:j==2?vr[0].z:vr[0].w;
            float v1 = j==0?vr[1].x:j==1?vr[1].y:j==2?vr[1].z:vr[1].w;
            float v2 = j==0?vr[2].x:j==1?vr[2].y:j==2?vr[2].z:vr[2].w;
            float v3 = j==0?vr[3].x:j==1?vr[3].y:j==2?vr[3].z:vr[3].w;
            *(unsigned long long*)&Vs[(vd0 + j) * STRB + vk0] = pack4bf(v0, v1, v2, v3);
        }
    };

    // ---- stage Q tile (256B-coalesced float4 loads) ----
    #pragma unroll
    for (int i = 0; i < 4; ++i) {
        int gq = q0 + rr + 16 * i;
        float4 x = (gq < SEQ) ? *(const float4*)(Qb + gq * DIM + cc)
                              : float4{0, 0, 0, 0};
        *(unsigned long long*)&Qs[(rr + 16 * i) * STRB + cc] = pack4bf(x.x, x.y, x.z, x.w);
    }
    __syncthreads();

    // hoist loop-invariant Q fragments; Qs becomes the P bf16 buffer
    const bf16x8 aq0 = *(const bf16x8*)&Qs[(qrow + l15) * STRB + quad * 8];
    const bf16x8 aq1 = *(const bf16x8*)&Qs[(qrow + l15) * STRB + 32 + quad * 8];

    // preload tiles 0 and 1 (2-deep)
    load_k(0,   krA); load_v(0,   vrA); load_mask(0,   mrA);
    load_k(64,  krB); load_v(64,  vrB); load_mask(64,  mrB);

    f32x4 oacc[4];
    #pragma unroll
    for (int dt = 0; dt < 4; ++dt) {
        oacc[dt][0]=0.f; oacc[dt][1]=0.f; oacc[dt][2]=0.f; oacc[dt][3]=0.f;
    }

    auto step = [&](int kt, float4 (&kr)[4], float4 (&vr)[4], i32x4a (&mr)[4]) {
        const int k0 = kt * 64;

        __syncthreads();            // prev tile's Ks/Vs readers done
        drain_mask(mr);             // waits only THIS set's loads (oldest in queue)
        drain_kv(kr, vr);
        __syncthreads();            // staging visible

        // refill this set with tile kt+2 (stays in flight for ~2 phases)
        if (kt + 2 < NT) {
            load_k(k0 + 128, kr); load_v(k0 + 128, vr); load_mask(k0 + 128, mr);
        }

        // ---- QK^T ----
        f32x4 sacc[4];
        #pragma unroll
        for (int nt2 = 0; nt2 < 4; ++nt2) {
            bf16x8 bk0 = *(const bf16x8*)&Ks[(nt2 * 16 + l15) * STRB + quad * 8];
            bf16x8 bk1 = *(const bf16x8*)&Ks[(nt2 * 16 + l15) * STRB + 32 + quad * 8];
            f32x4 c; c[0]=0.f; c[1]=0.f; c[2]=0.f; c[3]=0.f;
            c = __builtin_amdgcn_mfma_f32_16x16x32_bf16(aq0, bk0, c, 0, 0, 0);
            c = __builtin_amdgcn_mfma_f32_16x16x32_bf16(aq1, bk1, c, 0, 0, 0);
            sacc[nt2] = c;
        }

        // ---- scale, mask (from LDS), tanh, zero-diag; write P fp32+bf16 ----
        #pragma unroll
        for (int nt2 = 0; nt2 < 4; ++nt2) {
            int col = nt2 * 16 + l15;
            int gk  = k0 + col;
            #pragma unroll
            for (int r = 0; r < 4; ++r) {
                int qloc = qrow + quad * 4 + r;
                int gq = q0 + qloc;
                int m = Mint[qloc * STRW + col];
                float sv = sacc[nt2][r] * 0.125f;       // 1/sqrt(64)
                bool msk = (m == 0);
                float p = fast_tanh(msk ? -1e9f : sv);
                if (msk) p = -1.0f;
                if (gq == gk) p = 0.0f;                 // ignore_diag
                if (gq >= SEQ || gk >= SEQ) p = 0.0f;   // padding
                Pf[qloc * STRW + col] = p;              // in-place over mask
                Qs[qloc * STRB + col] = f2bf(p);
            }
        }

        // ---- attention write-out: wave-private rows, row-contiguous float4 ----
        #pragma unroll
        for (int i = 0; i < 4; ++i) {
            int row = prow + 4 * i;
            int gq  = q0 + row;
            int gk  = k0 + pcol;
            f32x4 pv = *(const f32x4*)&Pf[row * STRW + pcol];
            if (gq < SEQ) {
                if (gk + 3 < SEQ) {
                    *(f32x4a*)(Ab + (size_t)gq * SEQ + gk) = pv;
                } else {
                    #pragma unroll
                    for (int e = 0; e < 4; ++e)
                        if (gk + e < SEQ) Ab[(size_t)gq * SEQ + gk + e] = pv[e];
                }
            }
        }

        // ---- PV ----
        const bf16x8 ap0 = *(const bf16x8*)&Qs[(qrow + l15) * STRB + quad * 8];
        const bf16x8 ap1 = *(const bf16x8*)&Qs[(qrow + l15) * STRB + 32 + quad * 8];
        #pragma unroll
        for (int dt = 0; dt < 4; ++dt) {
            bf16x8 bv0 = *(const bf16x8*)&Vs[(dt * 16 + l15) * STRB + quad * 8];
            bf16x8 bv1 = *(const bf16x8*)&Vs[(dt * 16 + l15) * STRB + 32 + quad * 8];
            oacc[dt] = __builtin_amdgcn_mfma_f32_16x16x32_bf16(ap0, bv0, oacc[dt], 0, 0, 0);
            oacc[dt] = __builtin_amdgcn_mfma_f32_16x16x32_bf16(ap1, bv1, oacc[dt], 0, 0, 0);
        }
    };

    // ping-pong the two prefetch sets (NT=12 even -> clean 2x unroll)
    for (int kt = 0; kt < NT; kt += 2) {
        step(kt,     krA, vrA, mrA);
        step(kt + 1, krB, vrB, mrB);
    }

    // ---- epilogue: stage out tile in Pf (wave-private), write float4 ----
    #pragma unroll
    for (int dt = 0; dt < 4; ++dt)
        #pragma unroll
        for (int r = 0; r < 4; ++r)
            Pf[(qrow + quad * 4 + r) * STRW + dt * 16 + l15] = oacc[dt][r];
    #pragma unroll
    for (int i = 0; i < 4; ++i) {
        int row = prow + 4 * i;
        int gq  = q0 + row;
        f32x4 ov = *(const f32x4*)&Pf[row * STRW + pcol];
        if (gq < SEQ) *(f32x4*)(Ob + (size_t)gq * DIM + pcol) = ov;  // 16B-aligned
    }
}

extern "C" void kernel_launch(void* const* d_in, const int* in_sizes, int n_in,
                              void* d_out, int out_size, void* d_ws, size_t ws_size,
                              hipStream_t stream) {
    const float* Q = (const float*)d_in[0];
    const float* K = (const float*)d_in[1];
    const float* V = (const float*)d_in[2];
    const int*   M = (const int*)d_in[3];
    float* Out  = (float*)d_out;
    float* Attn = Out + (size_t)BATCH * SEQ * DIM;   // tuple order: (out, attention)
    dim3 grid(NT, BATCH);
    attn_kernel<<<grid, 256, 0, stream>>>(Q, K, V, M, Out, Attn);
}